// Round 4
// baseline (440.355 us; speedup 1.0000x reference)
//
#include <hip/hip_runtime.h>
#include <stdint.h>

#define B_ 16
#define C_ 512
#define N_ 4096
#define KS_ 4              // split-K factor for the Gram GEMM

typedef float f32x4 __attribute__((ext_vector_type(4)));
typedef __bf16 bf16x8 __attribute__((ext_vector_type(8)));

// fp32 -> bf16 round-to-nearest-even
static __device__ __forceinline__ unsigned short f2bf(float f) {
    unsigned int u = __float_as_uint(f);
    u += 0x7fffu + ((u >> 16) & 1u);
    return (unsigned short)(u >> 16);
}

// async global->LDS, 16B per lane (global_load_lds_dwordx4)
static __device__ __forceinline__ void gload_lds16(const void* g, void* l) {
    __builtin_amdgcn_global_load_lds(
        (__attribute__((address_space(1))) unsigned int*)(g),
        (__attribute__((address_space(3))) unsigned int*)(l),
        16, 0, 0);
}

// ---------------------------------------------------------------------------
// Kernel 1: x (fp32, BxCxN) -> q16 (bf16, BxCxN) AND qt16 (bf16, BxNxC).
// Pure-register 8c x 4n micro-transpose per thread: no LDS, no barriers,
// no bank conflicts. Block covers 128 c x 64 n.
//   reads : 8 x float4, 256 B contiguous per 16-lane row group
//   q16   : 8 x ushort4, 128 B per row group
//   qt16  : 4 x 16 B,    64 B per row group
// ---------------------------------------------------------------------------
__global__ __launch_bounds__(256)
void convert_transpose(const float* __restrict__ x,
                       unsigned short* __restrict__ q16,
                       unsigned short* __restrict__ qt16) {
    int b  = blockIdx.z;
    int n0 = blockIdx.x * 64  + (threadIdx.x & 15) * 4;
    int c0 = blockIdx.y * 128 + (threadIdx.x >> 4) * 8;

    const float*    xb  = x   + (size_t)b * C_ * N_;
    unsigned short* qb  = q16 + (size_t)b * C_ * N_;
    unsigned short* qtb = qt16 + (size_t)b * N_ * C_;

    unsigned short hv[8][4];
#pragma unroll
    for (int cc = 0; cc < 8; ++cc) {
        float4 v = *(const float4*)(xb + (size_t)(c0 + cc) * N_ + n0);
        hv[cc][0] = f2bf(v.x); hv[cc][1] = f2bf(v.y);
        hv[cc][2] = f2bf(v.z); hv[cc][3] = f2bf(v.w);
        ushort4 p; p.x = hv[cc][0]; p.y = hv[cc][1]; p.z = hv[cc][2]; p.w = hv[cc][3];
        *(ushort4*)(qb + (size_t)(c0 + cc) * N_ + n0) = p;
    }
#pragma unroll
    for (int nn = 0; nn < 4; ++nn) {
        unsigned short hh[8];
#pragma unroll
        for (int cc = 0; cc < 8; ++cc) hh[cc] = hv[cc][nn];
        *(uint4*)(qtb + (size_t)(n0 + nn) * C_ + c0) = *(uint4*)hh;   // 16 B store
    }
}

// ---------------------------------------------------------------------------
// Kernel 2: partial Gram, split-K, 128x64 tile (high occupancy variant).
//   epart[ks][b] = Q[b][:, ks*1024:(ks+1)*1024] . Q^T   (fp32)
// Flat grid 2048: slice = bid&63 pins each (b,ks) slice to one XCD (bid%8).
// LDS 12 KB, acc 4x2 -> ~6 blocks/CU. Symmetric -> transposed float4 stores.
// ---------------------------------------------------------------------------
__global__ __launch_bounds__(256, 6)
void gemm_gram_splitk(const unsigned short* __restrict__ q16,
                      float* __restrict__ epart) {
    int bid   = blockIdx.x;
    int slice = bid & 63;                  // b*KS + ks ; constant XCD per slice
    int b = slice >> 2, ks = slice & 3;
    int tile = bid >> 6;                   // 0..31
    int n0 = (tile & 7) * 64;              // B rows (d)
    int m0 = (tile >> 3) * 128;            // A rows (c)

    const int Kc = N_ / KS_;               // 1024
    const char* Qb = (const char*)(q16 + (size_t)b * C_ * N_) + (size_t)ks * Kc * 2;
    const int row_bytes = N_ * 2;

    __shared__ unsigned short As[128 * 32];   // 8 KB
    __shared__ unsigned short Bs[64 * 32];    // 4 KB

    int t = threadIdx.x;
    int lane = t & 63, wave = t >> 6;
    int wm = (wave >> 1) * 64, wn = (wave & 1) * 32;
    int qd = lane >> 4, r = lane & 15;

    f32x4 acc[4][2] = {};

    for (int k0 = 0; k0 < Kc; k0 += 32) {
        __syncthreads();
        {
            int o = t * 16;
            gload_lds16(Qb + (size_t)(m0 + (o >> 6)) * row_bytes + k0 * 2 + (o & 63),
                        (char*)As + o);
            int o2 = o + 4096;
            gload_lds16(Qb + (size_t)(m0 + (o2 >> 6)) * row_bytes + k0 * 2 + (o2 & 63),
                        (char*)As + o2);
            gload_lds16(Qb + (size_t)(n0 + (o >> 6)) * row_bytes + k0 * 2 + (o & 63),
                        (char*)Bs + o);
        }
        __syncthreads();

        bf16x8 af[4], bfr[2];
#pragma unroll
        for (int i = 0; i < 4; ++i)
            af[i] = *(const bf16x8*)&As[(wm + i * 16 + r) * 32 + qd * 8];
#pragma unroll
        for (int j = 0; j < 2; ++j)
            bfr[j] = *(const bf16x8*)&Bs[(wn + j * 16 + r) * 32 + qd * 8];
#pragma unroll
        for (int i = 0; i < 4; ++i)
#pragma unroll
            for (int j = 0; j < 2; ++j)
                acc[i][j] = __builtin_amdgcn_mfma_f32_16x16x32_bf16(af[i], bfr[j], acc[i][j], 0, 0, 0);
    }

    // symmetric: store D[c,d] at [d,c] -> contiguous float4 stores
    float* Db = epart + (size_t)(ks * B_ + b) * C_ * C_;
#pragma unroll
    for (int i = 0; i < 4; ++i)
#pragma unroll
        for (int j = 0; j < 2; ++j) {
            int cbase = m0 + wm + i * 16 + qd * 4;
            int d     = n0 + wn + j * 16 + r;
            *(f32x4*)(Db + (size_t)d * C_ + cbase) = acc[i][j];
        }
}

// ---------------------------------------------------------------------------
// Kernel 3: attention = softmax(-sum_s epart[s]), row-wise; bf16 out.
// ---------------------------------------------------------------------------
__global__ __launch_bounds__(256)
void softmax_neg4(const float* __restrict__ epart, unsigned short* __restrict__ att) {
    size_t row = blockIdx.x;                     // b*C + c
    const size_t slice = (size_t)B_ * C_ * C_;
    const float* e = epart + row * C_;
    int t = threadIdx.x;

    float e0 = 0.f, e1 = 0.f;
#pragma unroll
    for (int s = 0; s < KS_; ++s) {
        e0 += e[s * slice + t];
        e1 += e[s * slice + t + 256];
    }
    float m = fminf(e0, e1);                     // min(e) == -max(-e)
#pragma unroll
    for (int off = 32; off > 0; off >>= 1) m = fminf(m, __shfl_down(m, off, 64));
    __shared__ float red[8];
    if ((t & 63) == 0) red[t >> 6] = m;
    __syncthreads();
    m = fminf(fminf(red[0], red[1]), fminf(red[2], red[3]));

    float p0 = __expf(m - e0), p1 = __expf(m - e1);
    float s = p0 + p1;
#pragma unroll
    for (int off = 32; off > 0; off >>= 1) s += __shfl_down(s, off, 64);
    if ((t & 63) == 0) red[4 + (t >> 6)] = s;
    __syncthreads();
    s = red[4] + red[5] + red[6] + red[7];
    float inv = 1.0f / s;

    att[row * C_ + t]       = f2bf(p0 * inv);
    att[row * C_ + t + 256] = f2bf(p1 * inv);
}

// ---------------------------------------------------------------------------
// Kernel 4: y = gamma*(att . Q) + x, computed transposed:
//   D[n, c] = sum_d qt[n,d] * att[c,d]  == out[c,n]
// 128(n) x 64(c) tile, flat grid 4096: b = bid&15 pins batch to XCD (bid%8).
// float4 epilogue (4 consecutive n per acc reg). Writes d_out last.
// ---------------------------------------------------------------------------
__global__ __launch_bounds__(256, 6)
void gemm_out_t(const unsigned short* __restrict__ att,
                const unsigned short* __restrict__ qt16,
                const float* __restrict__ x,
                const float* __restrict__ gamma,
                float* __restrict__ y) {
    const int K = C_;                            // 512
    int bid  = blockIdx.x;
    int b    = bid & 15;                         // XCD-pinned batch
    int tile = bid >> 4;                         // 0..255
    int m0 = (tile & 31) * 128;                  // n
    int n0 = (tile >> 5) * 64;                   // c

    const char* Ab = (const char*)(qt16 + (size_t)b * N_ * C_);  // rows n, contig d
    const char* Bb = (const char*)(att  + (size_t)b * C_ * C_);  // rows c, contig d
    const int row_bytes = C_ * 2;                // 1024

    __shared__ unsigned short As[128 * 32];      // 8 KB
    __shared__ unsigned short Bs[64 * 32];       // 4 KB

    int t = threadIdx.x;
    int lane = t & 63, wave = t >> 6;
    int wm = (wave >> 1) * 64, wn = (wave & 1) * 32;
    int qd = lane >> 4, r = lane & 15;

    f32x4 acc[4][2] = {};

    for (int k0 = 0; k0 < K; k0 += 32) {
        __syncthreads();
        {
            int o = t * 16;
            gload_lds16(Ab + (size_t)(m0 + (o >> 6)) * row_bytes + k0 * 2 + (o & 63),
                        (char*)As + o);
            int o2 = o + 4096;
            gload_lds16(Ab + (size_t)(m0 + (o2 >> 6)) * row_bytes + k0 * 2 + (o2 & 63),
                        (char*)As + o2);
            gload_lds16(Bb + (size_t)(n0 + (o >> 6)) * row_bytes + k0 * 2 + (o & 63),
                        (char*)Bs + o);
        }
        __syncthreads();

        bf16x8 af[4], bfr[2];
#pragma unroll
        for (int i = 0; i < 4; ++i)
            af[i] = *(const bf16x8*)&As[(wm + i * 16 + r) * 32 + qd * 8];
#pragma unroll
        for (int j = 0; j < 2; ++j)
            bfr[j] = *(const bf16x8*)&Bs[(wn + j * 16 + r) * 32 + qd * 8];
#pragma unroll
        for (int i = 0; i < 4; ++i)
#pragma unroll
            for (int j = 0; j < 2; ++j)
                acc[i][j] = __builtin_amdgcn_mfma_f32_16x16x32_bf16(af[i], bfr[j], acc[i][j], 0, 0, 0);
    }

    float g = gamma[0];
    const float* xb = x + (size_t)b * C_ * N_;
    float*       yb = y + (size_t)b * C_ * N_;
#pragma unroll
    for (int i = 0; i < 4; ++i)
#pragma unroll
        for (int j = 0; j < 2; ++j) {
            int nbase = m0 + wm + i * 16 + qd * 4;   // 4 consecutive n
            int c     = n0 + wn + j * 16 + r;
            size_t idx = (size_t)c * N_ + nbase;
            float4 xv = *(const float4*)(xb + idx);
            f32x4 a = acc[i][j];
            float4 o;
            o.x = g * a[0] + xv.x;
            o.y = g * a[1] + xv.y;
            o.z = g * a[2] + xv.z;
            o.w = g * a[3] + xv.w;
            *(float4*)(yb + idx) = o;
        }
}

// ---------------------------------------------------------------------------
// Workspace (142,606,336 B total, proven safe):
//   q16   @ 0          : 67,108,864
//   qt16  @ 67,108,864 : 67,108,864
//   att16 @ 134,217,728:  8,388,608
// epart (67,108,864 B fp32) lives in d_out (134 MB), dead until gemm_out_t.
// ---------------------------------------------------------------------------
extern "C" void kernel_launch(void* const* d_in, const int* in_sizes, int n_in,
                              void* d_out, int out_size, void* d_ws, size_t ws_size,
                              hipStream_t stream) {
    const float* x     = (const float*)d_in[0];
    const float* gamma = (const float*)d_in[1];
    float*       y     = (float*)d_out;

    char* ws = (char*)d_ws;
    unsigned short* q16   = (unsigned short*)(ws);
    unsigned short* qt16  = (unsigned short*)(ws + 67108864);
    unsigned short* att16 = (unsigned short*)(ws + 134217728);
    float*          epart = (float*)d_out;            // scratch until final GEMM

    convert_transpose<<<dim3(N_ / 64, C_ / 128, B_), dim3(256), 0, stream>>>(x, q16, qt16);
    gemm_gram_splitk<<<dim3(2048), dim3(256), 0, stream>>>(q16, epart);
    softmax_neg4<<<dim3(B_ * C_), dim3(256), 0, stream>>>(epart, att16);
    gemm_out_t<<<dim3(4096), dim3(256), 0, stream>>>(att16, qt16, x, gamma, y);
}